// Round 17
// baseline (110.378 us; speedup 1.0000x reference)
//
#include <hip/hip_runtime.h>
#include <math.h>

#define NNODES 50000
#define NEDGES 1600000
#define BINSZ 128                  // nodes per bin (bin = c >> 7)
#define NBINS 391                  // ceil(50000/128)
#define NBLK 1000                  // sorter blocks
#define EPB (NEDGES / NBLK)        // 1600 edges per chunk
#define HALF 500                   // chunks per accum part
#define PCAP 2560                  // per-(bin,part) capacity (mean 2046, +11 sigma)
#define SCALE 0.17677669529663687f // 1/sqrt(32)

// Constant table C[] (LDS, 180 floats), built redundantly per block (5.7k MACs):
//   A[h][a][b]  : 0   + h*16 + a*4 + b   (Wq_h^T Wk_h)
//   U[h][b]     : 64  + h*4 + b          (bq_h^T Wk_h)   pairs with x[c]
//   V[h][a]     : 80  + h*4 + a          (Wq_h^T bk_h)   pairs with x[r]
//   W0[h]       : 96  + h                (bq_h . bk_h)
//   M[h][o][a]  : 100 + h*16 + o*4 + a   (Wo[o,hslice] . Wv_h[:,a])
//   N[h][o]     : 164 + h*4 + o          (Wo[o,hslice] . bv_h)
__device__ __forceinline__ void compute_C_entry(int t,
        const float* Wq, const float* bq, const float* Wk, const float* bk,
        const float* Wv, const float* bv, const float* Wo, float* C_lds) {
    if (t < 64) {
        int h = t >> 4, a = (t >> 2) & 3, b = t & 3;
        float s = 0.f;
        for (int k = 0; k < 32; k++) s += Wq[(h * 32 + k) * 4 + a] * Wk[(h * 32 + k) * 4 + b];
        C_lds[t] = s;
    } else if (t < 80) {
        int h = (t - 64) >> 2, b = (t - 64) & 3;
        float s = 0.f;
        for (int k = 0; k < 32; k++) s += bq[h * 32 + k] * Wk[(h * 32 + k) * 4 + b];
        C_lds[t] = s;
    } else if (t < 96) {
        int h = (t - 80) >> 2, a = (t - 80) & 3;
        float s = 0.f;
        for (int k = 0; k < 32; k++) s += Wq[(h * 32 + k) * 4 + a] * bk[h * 32 + k];
        C_lds[t] = s;
    } else if (t < 100) {
        int h = t - 96;
        float s = 0.f;
        for (int k = 0; k < 32; k++) s += bq[h * 32 + k] * bk[h * 32 + k];
        C_lds[t] = s;
    } else if (t < 164) {
        int i = t - 100;
        int h = i >> 4, o = (i >> 2) & 3, a = i & 3;
        float s = 0.f;
        for (int k = 0; k < 32; k++) s += Wo[o * 128 + h * 32 + k] * Wv[(h * 32 + k) * 4 + a];
        C_lds[t] = s;
    } else if (t < 180) {
        int i = t - 164;
        int h = i >> 2, o = i & 3;
        float s = 0.f;
        for (int k = 0; k < 32; k++) s += Wo[o * 128 + h * 32 + k] * bv[h * 32 + k];
        C_lds[t] = s;
    }
}

// LDS counting-sort per 1600-edge chunk -> contiguous chunk write + one
// contiguous directory row. Single-wave shfl scan, 2 barriers.
__global__ __launch_bounds__(256) void k_binA(const int* __restrict__ ei,
                                              unsigned* __restrict__ chunks,
                                              unsigned* __restrict__ dir) {
    __shared__ unsigned raw[EPB];
    __shared__ unsigned srt[EPB];
    __shared__ int hist[512];
    __shared__ int ofs[512];
    int t = threadIdx.x, blk = blockIdx.x;
    hist[t] = 0; hist[t + 256] = 0;
    __syncthreads();
    int e0 = blk * EPB;
    for (int i = t; i < EPB; i += 256) {
        int r = ei[e0 + i];
        int c = ei[NEDGES + e0 + i];
        raw[i] = ((unsigned)c << 16) | (unsigned)r;
        atomicAdd(&hist[c >> 7], 1);
    }
    __syncthreads();
    if (t < 64) {
        int v[8], run = 0;
#pragma unroll
        for (int j = 0; j < 8; j++) { v[j] = hist[8 * t + j]; run += v[j]; }
        int p = run;
#pragma unroll
        for (int off = 1; off < 64; off <<= 1) {
            int u = __shfl_up(p, off, 64);
            if (t >= off) p += u;
        }
        int base = p - run;
#pragma unroll
        for (int j = 0; j < 8; j++) {
            hist[8 * t + j] = base;
            ofs[8 * t + j] = base;
            base += v[j];
        }
    }
    __syncthreads();
    for (int i = t; i < EPB; i += 256) {
        unsigned v = raw[i];
        int pos = atomicAdd(&ofs[v >> 23], 1);
        srt[pos] = v;
    }
    __syncthreads();
    uint4* co = (uint4*)(chunks + (size_t)blk * EPB);
    const uint4* si = (const uint4*)srt;
    for (int i = t; i < EPB / 4; i += 256) co[i] = si[i];
    for (int b = t; b < NBINS; b += 256) {
        int start = hist[b];
        int len = ofs[b] - start;
        dir[(size_t)blk * NBINS + b] = ((unsigned)start << 16) | (unsigned)len;
    }
}

// tiled transpose: dir[1000][391] -> dirT[391][1000]
__global__ __launch_bounds__(256) void k_tr(const unsigned* __restrict__ dir,
                                            unsigned* __restrict__ dirT) {
    __shared__ unsigned tile[32][33];
    int bi = blockIdx.x % 13;
    int bj = blockIdx.x / 13;
    int tx = threadIdx.x & 31, ty = threadIdx.x >> 5;
    int col = bi * 32 + tx;
#pragma unroll
    for (int k = 0; k < 4; k++) {
        int row = bj * 32 + ty + k * 8;
        if (row < NBLK && col < NBINS) tile[ty + k * 8][tx] = dir[(size_t)row * NBINS + col];
    }
    __syncthreads();
    int col2 = bj * 32 + tx;
#pragma unroll
    for (int k = 0; k < 4; k++) {
        int row2 = bi * 32 + ty + k * 8;
        if (row2 < NBINS && col2 < NBLK) dirT[(size_t)row2 * NBLK + col2] = tile[tx][ty + k * 8];
    }
}

// (identical to R16's k_accum)
__global__ __launch_bounds__(256) void k_accum(
        const unsigned* __restrict__ chunks, const unsigned* __restrict__ dirT,
        const float* __restrict__ x,
        const float* __restrict__ Wq, const float* __restrict__ bq,
        const float* __restrict__ Wk, const float* __restrict__ bk,
        const float* __restrict__ Wv, const float* __restrict__ bv,
        const float* __restrict__ Wo,
        float* __restrict__ acc, float* __restrict__ pS) {
    __shared__ float Cl[192];
    __shared__ float pe[BINSZ][20];
    __shared__ unsigned raw[PCAP];
    __shared__ unsigned short srt[PCAP];
    __shared__ int hist[BINSZ];
    __shared__ int ofs[BINSZ];
    __shared__ int runStart[HALF];
    __shared__ int srcBase[HALF];
    __shared__ int wsum[4];
    __shared__ float sw[4][4];
    int bid = blockIdx.x;
    int bin = bid >> 1;
    int part = bid & 1;
    int t = threadIdx.x;
    int base = bin << 7;
    compute_C_entry(t, Wq, bq, Wk, bk, Wv, bv, Wo, Cl);
    if (t < BINSZ) hist[t] = 0;
    __syncthreads();
    if (t < BINSZ) {
        int node = base + t;
        if (node < NNODES) {
            float4 xv = ((const float4*)x)[node];
            float pr[20];
#pragma unroll
            for (int h = 0; h < 4; h++) {
#pragma unroll
                for (int a = 0; a < 4; a++) {
                    float g = Cl[80 + h * 4 + a]
                            + Cl[h * 16 + a * 4 + 0] * xv.x + Cl[h * 16 + a * 4 + 1] * xv.y
                            + Cl[h * 16 + a * 4 + 2] * xv.z + Cl[h * 16 + a * 4 + 3] * xv.w;
                    pr[h * 4 + a] = g * SCALE;
                }
                float e = Cl[96 + h]
                        + Cl[64 + h * 4 + 0] * xv.x + Cl[64 + h * 4 + 1] * xv.y
                        + Cl[64 + h * 4 + 2] * xv.z + Cl[64 + h * 4 + 3] * xv.w;
                pr[16 + h] = e * SCALE;
            }
#pragma unroll
            for (int q = 0; q < 5; q++) ((float4*)pe[t])[q] = ((const float4*)pr)[q];
        }
    }
    uint2 dd = {0u, 0u};
    int cnt = 0;
    if (t < HALF / 2) {
        dd = *(const uint2*)(dirT + (size_t)bin * NBLK + part * HALF + 2 * t);
        cnt = (int)(dd.x & 0xFFFFu) + (int)(dd.y & 0xFFFFu);
    }
    int lane = t & 63, w = t >> 6;
    int p = cnt;
#pragma unroll
    for (int off = 1; off < 64; off <<= 1) {
        int u = __shfl_up(p, off, 64);
        if (lane >= off) p += u;
    }
    if (lane == 63) wsum[w] = p;
    __syncthreads();
    int wbase = 0;
#pragma unroll
    for (int ww = 0; ww < 4; ww++) wbase += (ww < w) ? wsum[ww] : 0;
    int off0 = wbase + p - cnt;
    int nval = wsum[0] + wsum[1] + wsum[2] + wsum[3];
    if (nval > PCAP) nval = PCAP;
    if (t < HALF / 2) {
        int len0 = (int)(dd.x & 0xFFFFu);
        runStart[2 * t] = off0;
        runStart[2 * t + 1] = off0 + len0;
        srcBase[2 * t] = (part * HALF + 2 * t) * EPB + (int)(dd.x >> 16);
        srcBase[2 * t + 1] = (part * HALF + 2 * t + 1) * EPB + (int)(dd.y >> 16);
    }
    __syncthreads();
    for (int i = t; i < nval; i += 256) {
        int lo = 0, hi = HALF;
        while (hi - lo > 1) {
            int mid = (lo + hi) >> 1;
            if (runStart[mid] <= i) lo = mid; else hi = mid;
        }
        unsigned v = chunks[srcBase[lo] + (i - runStart[lo])];
        raw[i] = v;
        atomicAdd(&hist[(int)(v >> 16) - base], 1);
    }
    __syncthreads();
    if (t < 64) {
        int a0 = hist[2 * t], a1 = hist[2 * t + 1];
        int pair = a0 + a1;
        int pp = pair;
#pragma unroll
        for (int off = 1; off < 64; off <<= 1) {
            int u = __shfl_up(pp, off, 64);
            if (t >= off) pp += u;
        }
        int excl = pp - pair;
        hist[2 * t] = excl; hist[2 * t + 1] = excl + a0;
        ofs[2 * t] = excl;  ofs[2 * t + 1] = excl + a0;
    }
    __syncthreads();
    for (int i = t; i < nval; i += 256) {
        unsigned v = raw[i];
        int lc = (int)(v >> 16) - base;
        int pos = atomicAdd(&ofs[lc], 1);
        srt[pos] = (unsigned short)(v & 0xFFFFu);
    }
    __syncthreads();
    int nl = t >> 1;
    int sub = t & 1;
    int node = base + nl;
    int sBeg = hist[nl], sEnd = ofs[nl];
    float4 g0 = ((const float4*)pe[nl])[0];
    float4 g1 = ((const float4*)pe[nl])[1];
    float4 g2 = ((const float4*)pe[nl])[2];
    float4 g3 = ((const float4*)pe[nl])[3];
    float4 eh = ((const float4*)pe[nl])[4];
    float S0 = 0.f, S1 = 0.f, S2 = 0.f, S3 = 0.f;
    float4 y0 = {0, 0, 0, 0}, y1 = y0, y2 = y0, y3 = y0;
    for (int i = sBeg + sub; i < sEnd; i += 2) {
        int r = (int)srt[i];
        float4 xv = ((const float4*)x)[r];
        float p0 = __expf(xv.x * g0.x + xv.y * g0.y + xv.z * g0.z + xv.w * g0.w + eh.x);
        float p1 = __expf(xv.x * g1.x + xv.y * g1.y + xv.z * g1.z + xv.w * g1.w + eh.y);
        float p2 = __expf(xv.x * g2.x + xv.y * g2.y + xv.z * g2.z + xv.w * g2.w + eh.z);
        float p3 = __expf(xv.x * g3.x + xv.y * g3.y + xv.z * g3.z + xv.w * g3.w + eh.w);
        y0.x += p0 * xv.x; y0.y += p0 * xv.y; y0.z += p0 * xv.z; y0.w += p0 * xv.w;
        y1.x += p1 * xv.x; y1.y += p1 * xv.y; y1.z += p1 * xv.z; y1.w += p1 * xv.w;
        y2.x += p2 * xv.x; y2.y += p2 * xv.y; y2.z += p2 * xv.z; y2.w += p2 * xv.w;
        y3.x += p3 * xv.x; y3.y += p3 * xv.y; y3.z += p3 * xv.z; y3.w += p3 * xv.w;
        S0 += p0; S1 += p1; S2 += p2; S3 += p3;
    }
    y0.x += __shfl_xor(y0.x, 1); y0.y += __shfl_xor(y0.y, 1);
    y0.z += __shfl_xor(y0.z, 1); y0.w += __shfl_xor(y0.w, 1);
    y1.x += __shfl_xor(y1.x, 1); y1.y += __shfl_xor(y1.y, 1);
    y1.z += __shfl_xor(y1.z, 1); y1.w += __shfl_xor(y1.w, 1);
    y2.x += __shfl_xor(y2.x, 1); y2.y += __shfl_xor(y2.y, 1);
    y2.z += __shfl_xor(y2.z, 1); y2.w += __shfl_xor(y2.w, 1);
    y3.x += __shfl_xor(y3.x, 1); y3.y += __shfl_xor(y3.y, 1);
    y3.z += __shfl_xor(y3.z, 1); y3.w += __shfl_xor(y3.w, 1);
    S0 += __shfl_xor(S0, 1); S1 += __shfl_xor(S1, 1);
    S2 += __shfl_xor(S2, 1); S3 += __shfl_xor(S3, 1);
    if (node < NNODES) {
        float4* ap = (float4*)(acc + ((size_t)part * NNODES + node) * 20);
        float4 sv = {S0, S1, S2, S3};
        if (sub == 0) { ap[0] = y0; ap[2] = y2; ap[4] = sv; }
        else { ap[1] = y1; ap[3] = y3; }
    }
    float z0 = (sub == 0 && node < NNODES) ? S0 : 0.f;
    float z1 = (sub == 0 && node < NNODES) ? S1 : 0.f;
    float z2 = (sub == 0 && node < NNODES) ? S2 : 0.f;
    float z3 = (sub == 0 && node < NNODES) ? S3 : 0.f;
#pragma unroll
    for (int off = 1; off < 64; off <<= 1) {
        z0 += __shfl_xor(z0, off); z1 += __shfl_xor(z1, off);
        z2 += __shfl_xor(z2, off); z3 += __shfl_xor(z3, off);
    }
    if ((t & 63) == 0) { sw[w][0] = z0; sw[w][1] = z1; sw[w][2] = z2; sw[w][3] = z3; }
    __syncthreads();
    if (t == 0) {
        float4 v;
        v.x = sw[0][0] + sw[1][0] + sw[2][0] + sw[3][0];
        v.y = sw[0][1] + sw[1][1] + sw[2][1] + sw[3][1];
        v.z = sw[0][2] + sw[1][2] + sw[2][2] + sw[3][2];
        v.w = sw[0][3] + sw[1][3] + sw[2][3] + sw[3][3];
        ((float4*)pS)[bid] = v;
    }
}

__global__ __launch_bounds__(256) void k_out(
        const float* __restrict__ acc, const float* __restrict__ pS,
        const float* __restrict__ Wq, const float* __restrict__ bq,
        const float* __restrict__ Wk, const float* __restrict__ bk,
        const float* __restrict__ Wv, const float* __restrict__ bv,
        const float* __restrict__ Wo, const float* __restrict__ bo,
        const float* __restrict__ x, float* __restrict__ out) {
    __shared__ float Cl[192];
    __shared__ float sd[4][4];
    __shared__ float dd[4];
    int t = threadIdx.x;
    compute_C_entry(t, Wq, bq, Wk, bk, Wv, bv, Wo, Cl);
    float s0 = 0.f, s1 = 0.f, s2 = 0.f, s3 = 0.f;
    for (int i = t; i < 2 * NBINS; i += 256) {
        float4 v = ((const float4*)pS)[i];
        s0 += v.x; s1 += v.y; s2 += v.z; s3 += v.w;
    }
#pragma unroll
    for (int off = 1; off < 64; off <<= 1) {
        s0 += __shfl_xor(s0, off); s1 += __shfl_xor(s1, off);
        s2 += __shfl_xor(s2, off); s3 += __shfl_xor(s3, off);
    }
    int w = t >> 6;
    if ((t & 63) == 0) { sd[w][0] = s0; sd[w][1] = s1; sd[w][2] = s2; sd[w][3] = s3; }
    __syncthreads();
    if (t < 4) dd[t] = 1.f / (sd[0][t] + sd[1][t] + sd[2][t] + sd[3][t]);
    __syncthreads();
    int i = blockIdx.x * blockDim.x + t;
    if (i >= NNODES) return;
    const float4* a0 = (const float4*)(acc + (size_t)i * 20);
    const float4* a1 = (const float4*)(acc + ((size_t)NNODES + i) * 20);
    float4 y[4], S;
#pragma unroll
    for (int q = 0; q < 4; q++) {
        float4 u = a0[q], v = a1[q];
        y[q].x = u.x + v.x; y[q].y = u.y + v.y; y[q].z = u.z + v.z; y[q].w = u.w + v.w;
    }
    {
        float4 u = a0[4], v = a1[4];
        S.x = u.x + v.x; S.y = u.y + v.y; S.z = u.z + v.z; S.w = u.w + v.w;
    }
    float Sv[4] = {S.x, S.y, S.z, S.w};
    float di[4] = {dd[0], dd[1], dd[2], dd[3]};
    float o[4];
#pragma unroll
    for (int oo = 0; oo < 4; oo++) {
        float a = bo[oo];
#pragma unroll
        for (int h = 0; h < 4; h++) {
            float m = Cl[100 + h * 16 + oo * 4 + 0] * y[h].x
                    + Cl[100 + h * 16 + oo * 4 + 1] * y[h].y
                    + Cl[100 + h * 16 + oo * 4 + 2] * y[h].z
                    + Cl[100 + h * 16 + oo * 4 + 3] * y[h].w
                    + Cl[164 + h * 4 + oo] * Sv[h];
            a += di[h] * m;
        }
        o[oo] = a;
    }
    float4 xv = ((const float4*)x)[i];
    float4 ov;
    ov.x = o[0] + xv.x; ov.y = o[1] + xv.y; ov.z = o[2] + xv.z; ov.w = o[3] + xv.w;
    ((float4*)out)[i] = ov;
}

extern "C" void kernel_launch(void* const* d_in, const int* in_sizes, int n_in,
                              void* d_out, int out_size, void* d_ws, size_t ws_size,
                              hipStream_t stream) {
    const float* x = (const float*)d_in[0];
    const int* ei = (const int*)d_in[1];
    const float* Wq = (const float*)d_in[2];
    const float* bq = (const float*)d_in[3];
    const float* Wk = (const float*)d_in[4];
    const float* bk = (const float*)d_in[5];
    const float* Wv = (const float*)d_in[6];
    const float* bv = (const float*)d_in[7];
    const float* Wo = (const float*)d_in[8];
    const float* bo = (const float*)d_in[9];
    float* out = (float*)d_out;

    float* fws = (float*)d_ws;
    float* acc = fws;                                   // 2*NNODES*20 f32, 8 MB
    float* pS = acc + (size_t)2 * NNODES * 20;          // 2*NBINS float4
    unsigned* chunks = (unsigned*)(pS + (size_t)2 * NBINS * 4 + 4);  // NEDGES u32
    unsigned* dir = chunks + (size_t)NEDGES;            // NBLK*NBINS u32
    unsigned* dirT = dir + (size_t)NBLK * NBINS;        // NBINS*NBLK u32

    k_binA<<<NBLK, 256, 0, stream>>>(ei, chunks, dir);
    k_tr<<<13 * 32, 256, 0, stream>>>(dir, dirT);
    // MEASUREMENT ROUND: k_accum launched 3x (idempotent -- identical output).
    // T(R17) - T(R16) = 2*(accum + launch)  ->  localizes the hidden ~37us.
    k_accum<<<2 * NBINS, 256, 0, stream>>>(chunks, dirT, x, Wq, bq, Wk, bk, Wv, bv, Wo, acc, pS);
    k_accum<<<2 * NBINS, 256, 0, stream>>>(chunks, dirT, x, Wq, bq, Wk, bk, Wv, bv, Wo, acc, pS);
    k_accum<<<2 * NBINS, 256, 0, stream>>>(chunks, dirT, x, Wq, bq, Wk, bk, Wv, bv, Wo, acc, pS);
    k_out<<<(NNODES + 255) / 256, 256, 0, stream>>>(acc, pS,
                                                    Wq, bq, Wk, bk, Wv, bv, Wo, bo, x, out);
}

// Round 18
// 68.659 us; speedup vs baseline: 1.6076x; 1.6076x over previous
//
#include <hip/hip_runtime.h>
#include <math.h>

#define NNODES 50000
#define NEDGES 1600000
#define BINSZ 128                  // nodes per bin (bin = c >> 7)
#define NBINS 391                  // ceil(50000/128)
#define NBLK 1000                  // sorter blocks
#define EPB (NEDGES / NBLK)        // 1600 edges per chunk
#define NGRP 250                   // scatter groups (4 chunks each)
#define GSZ 4                      // chunks per group
#define GCAP 48                    // slots per (bin,group): mean 16.4, +7.8 sigma; 192B = 3 lines
#define PCAP 2560                  // per-(bin,half) valid-edge capacity (mean 2046, +11 sigma)
#define SCALE 0.17677669529663687f // 1/sqrt(32)

// Constant table C[] (LDS, 180 floats), built redundantly per block (5.7k MACs):
//   A[h][a][b]  : 0   + h*16 + a*4 + b   (Wq_h^T Wk_h)
//   U[h][b]     : 64  + h*4 + b          (bq_h^T Wk_h)   pairs with x[c]
//   V[h][a]     : 80  + h*4 + a          (Wq_h^T bk_h)   pairs with x[r]
//   W0[h]       : 96  + h                (bq_h . bk_h)
//   M[h][o][a]  : 100 + h*16 + o*4 + a   (Wo[o,hslice] . Wv_h[:,a])
//   N[h][o]     : 164 + h*4 + o          (Wo[o,hslice] . bv_h)
__device__ __forceinline__ void compute_C_entry(int t,
        const float* Wq, const float* bq, const float* Wk, const float* bk,
        const float* Wv, const float* bv, const float* Wo, float* C_lds) {
    if (t < 64) {
        int h = t >> 4, a = (t >> 2) & 3, b = t & 3;
        float s = 0.f;
        for (int k = 0; k < 32; k++) s += Wq[(h * 32 + k) * 4 + a] * Wk[(h * 32 + k) * 4 + b];
        C_lds[t] = s;
    } else if (t < 80) {
        int h = (t - 64) >> 2, b = (t - 64) & 3;
        float s = 0.f;
        for (int k = 0; k < 32; k++) s += bq[h * 32 + k] * Wk[(h * 32 + k) * 4 + b];
        C_lds[t] = s;
    } else if (t < 96) {
        int h = (t - 80) >> 2, a = (t - 80) & 3;
        float s = 0.f;
        for (int k = 0; k < 32; k++) s += Wq[(h * 32 + k) * 4 + a] * bk[h * 32 + k];
        C_lds[t] = s;
    } else if (t < 100) {
        int h = t - 96;
        float s = 0.f;
        for (int k = 0; k < 32; k++) s += bq[h * 32 + k] * bk[h * 32 + k];
        C_lds[t] = s;
    } else if (t < 164) {
        int i = t - 100;
        int h = i >> 4, o = (i >> 2) & 3, a = i & 3;
        float s = 0.f;
        for (int k = 0; k < 32; k++) s += Wo[o * 128 + h * 32 + k] * Wv[(h * 32 + k) * 4 + a];
        C_lds[t] = s;
    } else if (t < 180) {
        int i = t - 164;
        int h = i >> 2, o = i & 3;
        float s = 0.f;
        for (int k = 0; k < 32; k++) s += Wo[o * 128 + h * 32 + k] * bv[h * 32 + k];
        C_lds[t] = s;
    }
}

// LDS counting-sort per 1600-edge chunk -> contiguous chunk write + directory
// row. Edges encoded (c<<16)|(r+1) so 0 is an "empty" sentinel downstream.
__global__ __launch_bounds__(256) void k_binA(const int* __restrict__ ei,
                                              unsigned* __restrict__ chunks,
                                              unsigned* __restrict__ dir) {
    __shared__ unsigned raw[EPB];
    __shared__ unsigned srt[EPB];
    __shared__ int hist[512];
    __shared__ int ofs[512];
    int t = threadIdx.x, blk = blockIdx.x;
    hist[t] = 0; hist[t + 256] = 0;
    __syncthreads();
    int e0 = blk * EPB;
    for (int i = t; i < EPB; i += 256) {
        int r = ei[e0 + i];
        int c = ei[NEDGES + e0 + i];
        raw[i] = ((unsigned)c << 16) | (unsigned)(r + 1);
        atomicAdd(&hist[c >> 7], 1);
    }
    __syncthreads();
    // single-wave scan over 512 counters: lane L owns bins [8L, 8L+8)
    if (t < 64) {
        int v[8], run = 0;
#pragma unroll
        for (int j = 0; j < 8; j++) { v[j] = hist[8 * t + j]; run += v[j]; }
        int p = run;
#pragma unroll
        for (int off = 1; off < 64; off <<= 1) {
            int u = __shfl_up(p, off, 64);
            if (t >= off) p += u;
        }
        int base = p - run;
#pragma unroll
        for (int j = 0; j < 8; j++) {
            hist[8 * t + j] = base;
            ofs[8 * t + j] = base;
            base += v[j];
        }
    }
    __syncthreads();
    for (int i = t; i < EPB; i += 256) {
        unsigned v = raw[i];
        int pos = atomicAdd(&ofs[v >> 23], 1);
        srt[pos] = v;
    }
    __syncthreads();
    uint4* co = (uint4*)(chunks + (size_t)blk * EPB);
    const uint4* si = (const uint4*)srt;
    for (int i = t; i < EPB / 4; i += 256) co[i] = si[i];
    for (int b = t; b < NBINS; b += 256) {
        int start = hist[b];
        int len = ofs[b] - start;
        dir[(size_t)blk * NBINS + b] = ((unsigned)start << 16) | (unsigned)len;
    }
}

// Scatter sorted chunks into per-(bin,group) exclusive 192B regions.
// 250 blocks x 4 chunks; per-bin local offsets from the 4 staged dir rows --
// zero global coordination, zero cross-block line sharing (GCAP*4B = 3 lines).
__global__ __launch_bounds__(256) void k_scat(const unsigned* __restrict__ chunks,
                                              const unsigned* __restrict__ dir,
                                              unsigned* __restrict__ binned) {
    __shared__ unsigned dirL[GSZ][NBINS];
    __shared__ unsigned short loc[GSZ][NBINS];
    int g = blockIdx.x, t = threadIdx.x;
    for (int i = t; i < GSZ * NBINS; i += 256) {
        int j = i / NBINS, b = i - j * NBINS;
        dirL[j][b] = dir[(size_t)(g * GSZ + j) * NBINS + b];
    }
    __syncthreads();
    for (int b = t; b < NBINS; b += 256) {
        int run = 0;
#pragma unroll
        for (int j = 0; j < GSZ; j++) {
            loc[j][b] = (unsigned short)run;
            run += dirL[j][b] & 0xFFFFu;
        }
    }
    __syncthreads();
#pragma unroll
    for (int j = 0; j < GSZ; j++) {
        const unsigned* cp = chunks + (size_t)(g * GSZ + j) * EPB;
        for (int i = t; i < EPB; i += 256) {
            unsigned v = cp[i];
            int b = v >> 23;
            int pos = i - (int)(dirL[j][b] >> 16);
            int dl = (int)loc[j][b] + pos;
            if (dl < GCAP) binned[((size_t)b * NGRP + g) * GCAP + dl] = v;
        }
    }
}

// 782 blocks: bin = bid>>1, part = bid&1 owns groups [part*125, part*125+125).
// Streams its CONTIGUOUS 24KB region twice (uint4): hist pass, scatter pass.
// No dir walk, no binary search, no LDS raw staging (the R12-R16 28us cost).
__global__ __launch_bounds__(256) void k_accum(
        const unsigned* __restrict__ binned, const float* __restrict__ x,
        const float* __restrict__ Wq, const float* __restrict__ bq,
        const float* __restrict__ Wk, const float* __restrict__ bk,
        const float* __restrict__ Wv, const float* __restrict__ bv,
        const float* __restrict__ Wo,
        float* __restrict__ acc, float* __restrict__ pS) {
    __shared__ float Cl[192];
    __shared__ float pe[BINSZ][20];
    __shared__ unsigned short srt[PCAP];
    __shared__ int hist[BINSZ];
    __shared__ int ofs[BINSZ];
    __shared__ float sw[4][4];
    int bid = blockIdx.x;
    int bin = bid >> 1;
    int part = bid & 1;
    int t = threadIdx.x;
    int base = bin << 7;
    compute_C_entry(t, Wq, bq, Wk, bk, Wv, bv, Wo, Cl);
    if (t < BINSZ) hist[t] = 0;
    __syncthreads();
    // per-node score coefficients g[16], e[4]
    if (t < BINSZ) {
        int node = base + t;
        if (node < NNODES) {
            float4 xv = ((const float4*)x)[node];
            float pr[20];
#pragma unroll
            for (int h = 0; h < 4; h++) {
#pragma unroll
                for (int a = 0; a < 4; a++) {
                    float g = Cl[80 + h * 4 + a]
                            + Cl[h * 16 + a * 4 + 0] * xv.x + Cl[h * 16 + a * 4 + 1] * xv.y
                            + Cl[h * 16 + a * 4 + 2] * xv.z + Cl[h * 16 + a * 4 + 3] * xv.w;
                    pr[h * 4 + a] = g * SCALE;
                }
                float e = Cl[96 + h]
                        + Cl[64 + h * 4 + 0] * xv.x + Cl[64 + h * 4 + 1] * xv.y
                        + Cl[64 + h * 4 + 2] * xv.z + Cl[64 + h * 4 + 3] * xv.w;
                pr[16 + h] = e * SCALE;
            }
#pragma unroll
            for (int q = 0; q < 5; q++) ((float4*)pe[t])[q] = ((const float4*)pr)[q];
        }
    }
    __syncthreads();
    const uint4* reg = (const uint4*)(binned + ((size_t)bin * NGRP + part * (NGRP / 2)) * GCAP);
    const int RLEN4 = (NGRP / 2) * GCAP / 4;   // 1500 uint4
    // pass 1: histogram of valid edges (contiguous uint4 stream)
    for (int i = t; i < RLEN4; i += 256) {
        uint4 v4 = reg[i];
        if (v4.x) atomicAdd(&hist[(v4.x >> 16) & 127], 1);
        if (v4.y) atomicAdd(&hist[(v4.y >> 16) & 127], 1);
        if (v4.z) atomicAdd(&hist[(v4.z >> 16) & 127], 1);
        if (v4.w) atomicAdd(&hist[(v4.w >> 16) & 127], 1);
    }
    __syncthreads();
    // single-wave exclusive prefix over 128 counters (lane owns 2 bins)
    if (t < 64) {
        int a0 = hist[2 * t], a1 = hist[2 * t + 1];
        int pair = a0 + a1;
        int pp = pair;
#pragma unroll
        for (int off = 1; off < 64; off <<= 1) {
            int u = __shfl_up(pp, off, 64);
            if (t >= off) pp += u;
        }
        int excl = pp - pair;
        hist[2 * t] = excl; hist[2 * t + 1] = excl + a0;
        ofs[2 * t] = excl;  ofs[2 * t + 1] = excl + a0;
    }
    __syncthreads();
    // pass 2: scatter source ids into per-node contiguous segments
    for (int i = t; i < RLEN4; i += 256) {
        uint4 v4 = reg[i];
#pragma unroll
        for (int q = 0; q < 4; q++) {
            unsigned v = (q == 0) ? v4.x : (q == 1) ? v4.y : (q == 2) ? v4.z : v4.w;
            if (v) {
                int lc = (v >> 16) & 127;
                int pos = atomicAdd(&ofs[lc], 1);
                if (pos < PCAP) srt[pos] = (unsigned short)(v & 0xFFFFu);
            }
        }
    }
    __syncthreads();
    // accumulate: 2 lanes per node, registers only
    int nl = t >> 1;
    int sub = t & 1;
    int node = base + nl;
    int sBeg = hist[nl], sEnd = ofs[nl];
    if (sEnd > PCAP) sEnd = PCAP;
    float4 g0 = ((const float4*)pe[nl])[0];
    float4 g1 = ((const float4*)pe[nl])[1];
    float4 g2 = ((const float4*)pe[nl])[2];
    float4 g3 = ((const float4*)pe[nl])[3];
    float4 eh = ((const float4*)pe[nl])[4];
    float S0 = 0.f, S1 = 0.f, S2 = 0.f, S3 = 0.f;
    float4 y0 = {0, 0, 0, 0}, y1 = y0, y2 = y0, y3 = y0;
    for (int i = sBeg + sub; i < sEnd; i += 2) {
        int r = (int)srt[i] - 1;
        float4 xv = ((const float4*)x)[r];
        float p0 = __expf(xv.x * g0.x + xv.y * g0.y + xv.z * g0.z + xv.w * g0.w + eh.x);
        float p1 = __expf(xv.x * g1.x + xv.y * g1.y + xv.z * g1.z + xv.w * g1.w + eh.y);
        float p2 = __expf(xv.x * g2.x + xv.y * g2.y + xv.z * g2.z + xv.w * g2.w + eh.z);
        float p3 = __expf(xv.x * g3.x + xv.y * g3.y + xv.z * g3.z + xv.w * g3.w + eh.w);
        y0.x += p0 * xv.x; y0.y += p0 * xv.y; y0.z += p0 * xv.z; y0.w += p0 * xv.w;
        y1.x += p1 * xv.x; y1.y += p1 * xv.y; y1.z += p1 * xv.z; y1.w += p1 * xv.w;
        y2.x += p2 * xv.x; y2.y += p2 * xv.y; y2.z += p2 * xv.z; y2.w += p2 * xv.w;
        y3.x += p3 * xv.x; y3.y += p3 * xv.y; y3.z += p3 * xv.z; y3.w += p3 * xv.w;
        S0 += p0; S1 += p1; S2 += p2; S3 += p3;
    }
    y0.x += __shfl_xor(y0.x, 1); y0.y += __shfl_xor(y0.y, 1);
    y0.z += __shfl_xor(y0.z, 1); y0.w += __shfl_xor(y0.w, 1);
    y1.x += __shfl_xor(y1.x, 1); y1.y += __shfl_xor(y1.y, 1);
    y1.z += __shfl_xor(y1.z, 1); y1.w += __shfl_xor(y1.w, 1);
    y2.x += __shfl_xor(y2.x, 1); y2.y += __shfl_xor(y2.y, 1);
    y2.z += __shfl_xor(y2.z, 1); y2.w += __shfl_xor(y2.w, 1);
    y3.x += __shfl_xor(y3.x, 1); y3.y += __shfl_xor(y3.y, 1);
    y3.z += __shfl_xor(y3.z, 1); y3.w += __shfl_xor(y3.w, 1);
    S0 += __shfl_xor(S0, 1); S1 += __shfl_xor(S1, 1);
    S2 += __shfl_xor(S2, 1); S3 += __shfl_xor(S3, 1);
    if (node < NNODES) {
        float4* ap = (float4*)(acc + ((size_t)part * NNODES + node) * 20);
        float4 sv = {S0, S1, S2, S3};
        if (sub == 0) { ap[0] = y0; ap[2] = y2; ap[4] = sv; }
        else { ap[1] = y1; ap[3] = y3; }
    }
    // per-block S partial (plain store, reduced inside k_out)
    int lane = t & 63, w = t >> 6;
    float z0 = (sub == 0 && node < NNODES) ? S0 : 0.f;
    float z1 = (sub == 0 && node < NNODES) ? S1 : 0.f;
    float z2 = (sub == 0 && node < NNODES) ? S2 : 0.f;
    float z3 = (sub == 0 && node < NNODES) ? S3 : 0.f;
#pragma unroll
    for (int off = 1; off < 64; off <<= 1) {
        z0 += __shfl_xor(z0, off); z1 += __shfl_xor(z1, off);
        z2 += __shfl_xor(z2, off); z3 += __shfl_xor(z3, off);
    }
    if (lane == 0) { sw[w][0] = z0; sw[w][1] = z1; sw[w][2] = z2; sw[w][3] = z3; }
    __syncthreads();
    if (t == 0) {
        float4 v;
        v.x = sw[0][0] + sw[1][0] + sw[2][0] + sw[3][0];
        v.y = sw[0][1] + sw[1][1] + sw[2][1] + sw[3][1];
        v.z = sw[0][2] + sw[1][2] + sw[2][2] + sw[3][2];
        v.w = sw[0][3] + sw[1][3] + sw[2][3] + sw[3][3];
        ((float4*)pS)[bid] = v;
    }
}

// reduce per-block S partials + sum part accumulators + normalize + collapsed
// output projection + residual
__global__ __launch_bounds__(256) void k_out(
        const float* __restrict__ acc, const float* __restrict__ pS,
        const float* __restrict__ Wq, const float* __restrict__ bq,
        const float* __restrict__ Wk, const float* __restrict__ bk,
        const float* __restrict__ Wv, const float* __restrict__ bv,
        const float* __restrict__ Wo, const float* __restrict__ bo,
        const float* __restrict__ x, float* __restrict__ out) {
    __shared__ float Cl[192];
    __shared__ float sd[4][4];
    __shared__ float dd[4];
    int t = threadIdx.x;
    compute_C_entry(t, Wq, bq, Wk, bk, Wv, bv, Wo, Cl);
    float s0 = 0.f, s1 = 0.f, s2 = 0.f, s3 = 0.f;
    for (int i = t; i < 2 * NBINS; i += 256) {
        float4 v = ((const float4*)pS)[i];
        s0 += v.x; s1 += v.y; s2 += v.z; s3 += v.w;
    }
#pragma unroll
    for (int off = 1; off < 64; off <<= 1) {
        s0 += __shfl_xor(s0, off); s1 += __shfl_xor(s1, off);
        s2 += __shfl_xor(s2, off); s3 += __shfl_xor(s3, off);
    }
    int w = t >> 6;
    if ((t & 63) == 0) { sd[w][0] = s0; sd[w][1] = s1; sd[w][2] = s2; sd[w][3] = s3; }
    __syncthreads();
    if (t < 4) dd[t] = 1.f / (sd[0][t] + sd[1][t] + sd[2][t] + sd[3][t]);
    __syncthreads();
    int i = blockIdx.x * blockDim.x + t;
    if (i >= NNODES) return;
    const float4* a0 = (const float4*)(acc + (size_t)i * 20);
    const float4* a1 = (const float4*)(acc + ((size_t)NNODES + i) * 20);
    float4 y[4], S;
#pragma unroll
    for (int q = 0; q < 4; q++) {
        float4 u = a0[q], v = a1[q];
        y[q].x = u.x + v.x; y[q].y = u.y + v.y; y[q].z = u.z + v.z; y[q].w = u.w + v.w;
    }
    {
        float4 u = a0[4], v = a1[4];
        S.x = u.x + v.x; S.y = u.y + v.y; S.z = u.z + v.z; S.w = u.w + v.w;
    }
    float Sv[4] = {S.x, S.y, S.z, S.w};
    float di[4] = {dd[0], dd[1], dd[2], dd[3]};
    float o[4];
#pragma unroll
    for (int oo = 0; oo < 4; oo++) {
        float a = bo[oo];
#pragma unroll
        for (int h = 0; h < 4; h++) {
            float m = Cl[100 + h * 16 + oo * 4 + 0] * y[h].x
                    + Cl[100 + h * 16 + oo * 4 + 1] * y[h].y
                    + Cl[100 + h * 16 + oo * 4 + 2] * y[h].z
                    + Cl[100 + h * 16 + oo * 4 + 3] * y[h].w
                    + Cl[164 + h * 4 + oo] * Sv[h];
            a += di[h] * m;
        }
        o[oo] = a;
    }
    float4 xv = ((const float4*)x)[i];
    float4 ov;
    ov.x = o[0] + xv.x; ov.y = o[1] + xv.y; ov.z = o[2] + xv.z; ov.w = o[3] + xv.w;
    ((float4*)out)[i] = ov;
}

extern "C" void kernel_launch(void* const* d_in, const int* in_sizes, int n_in,
                              void* d_out, int out_size, void* d_ws, size_t ws_size,
                              hipStream_t stream) {
    const float* x = (const float*)d_in[0];
    const int* ei = (const int*)d_in[1];
    const float* Wq = (const float*)d_in[2];
    const float* bq = (const float*)d_in[3];
    const float* Wk = (const float*)d_in[4];
    const float* bk = (const float*)d_in[5];
    const float* Wv = (const float*)d_in[6];
    const float* bv = (const float*)d_in[7];
    const float* Wo = (const float*)d_in[8];
    const float* bo = (const float*)d_in[9];
    float* out = (float*)d_out;

    float* fws = (float*)d_ws;
    float* acc = fws;                                   // 2*NNODES*20 f32, 8 MB
    float* pS = acc + (size_t)2 * NNODES * 20;          // 782 float4 (pad to 3200)
    unsigned* chunks = (unsigned*)(pS + 3200);          // NEDGES u32, 6.4 MB
    unsigned* dir = chunks + (size_t)NEDGES;            // NBLK*NBINS u32, 1.56 MB
    unsigned* binned = dir + (size_t)NBLK * NBINS;      // NBINS*NGRP*GCAP u32, 18.8 MB

    hipMemsetAsync(binned, 0, (size_t)NBINS * NGRP * GCAP * 4, stream);
    k_binA<<<NBLK, 256, 0, stream>>>(ei, chunks, dir);
    k_scat<<<NGRP, 256, 0, stream>>>(chunks, dir, binned);
    k_accum<<<2 * NBINS, 256, 0, stream>>>(binned, x, Wq, bq, Wk, bk, Wv, bv, Wo, acc, pS);
    k_out<<<(NNODES + 255) / 256, 256, 0, stream>>>(acc, pS,
                                                    Wq, bq, Wk, bk, Wv, bv, Wo, bo, x, out);
}

// Round 19
// 54.655 us; speedup vs baseline: 2.0195x; 1.2562x over previous
//
#include <hip/hip_runtime.h>
#include <math.h>

#define NNODES 50000
#define NEDGES 1600000
#define BINSZ 128                  // nodes per bin (bin = c >> 7)
#define NBINS 391                  // ceil(50000/128)
#define NBLK 1000                  // sorter blocks
#define EPB (NEDGES / NBLK)        // 1600 edges per chunk
#define HALF 500                   // chunks per accum part
#define PCAP 2560                  // per-(bin,part) capacity (mean 2046, +11 sigma)
#define SCALE 0.17677669529663687f // 1/sqrt(32)

// Constant table C[] (180 floats):
//   A[h][a][b]  : 0   + h*16 + a*4 + b   (Wq_h^T Wk_h)
//   U[h][b]     : 64  + h*4 + b          (bq_h^T Wk_h)   pairs with x[c]
//   V[h][a]     : 80  + h*4 + a          (Wq_h^T bk_h)   pairs with x[r]
//   W0[h]       : 96  + h                (bq_h . bk_h)
//   M[h][o][a]  : 100 + h*16 + o*4 + a   (Wo[o,hslice] . Wv_h[:,a])
//   N[h][o]     : 164 + h*4 + o          (Wo[o,hslice] . bv_h)
__device__ __forceinline__ void compute_C_entry(int t,
        const float* Wq, const float* bq, const float* Wk, const float* bk,
        const float* Wv, const float* bv, const float* Wo, float* C_lds) {
    if (t < 64) {
        int h = t >> 4, a = (t >> 2) & 3, b = t & 3;
        float s = 0.f;
        for (int k = 0; k < 32; k++) s += Wq[(h * 32 + k) * 4 + a] * Wk[(h * 32 + k) * 4 + b];
        C_lds[t] = s;
    } else if (t < 80) {
        int h = (t - 64) >> 2, b = (t - 64) & 3;
        float s = 0.f;
        for (int k = 0; k < 32; k++) s += bq[h * 32 + k] * Wk[(h * 32 + k) * 4 + b];
        C_lds[t] = s;
    } else if (t < 96) {
        int h = (t - 80) >> 2, a = (t - 80) & 3;
        float s = 0.f;
        for (int k = 0; k < 32; k++) s += Wq[(h * 32 + k) * 4 + a] * bk[h * 32 + k];
        C_lds[t] = s;
    } else if (t < 100) {
        int h = t - 96;
        float s = 0.f;
        for (int k = 0; k < 32; k++) s += bq[h * 32 + k] * bk[h * 32 + k];
        C_lds[t] = s;
    } else if (t < 164) {
        int i = t - 100;
        int h = i >> 4, o = (i >> 2) & 3, a = i & 3;
        float s = 0.f;
        for (int k = 0; k < 32; k++) s += Wo[o * 128 + h * 32 + k] * Wv[(h * 32 + k) * 4 + a];
        C_lds[t] = s;
    } else if (t < 180) {
        int i = t - 164;
        int h = i >> 2, o = i & 3;
        float s = 0.f;
        for (int k = 0; k < 32; k++) s += Wo[o * 128 + h * 32 + k] * bv[h * 32 + k];
        C_lds[t] = s;
    }
}

// per-node score coefficients: proj[i][0..15] = g_h (SCALE*(A_h x + V_h)),
// proj[i][16..19] = e_h (SCALE*(U_h.x + W0_h)). Hoisted out of k_accum so the
// 782 accum blocks don't each rebuild C + coefficients (R19 ablation).
__global__ __launch_bounds__(256) void k_proj(const float* __restrict__ x,
        const float* __restrict__ Wq, const float* __restrict__ bq,
        const float* __restrict__ Wk, const float* __restrict__ bk,
        const float* __restrict__ Wv, const float* __restrict__ bv,
        const float* __restrict__ Wo, float* __restrict__ proj) {
    __shared__ float Cl[192];
    int t = threadIdx.x;
    compute_C_entry(t, Wq, bq, Wk, bk, Wv, bv, Wo, Cl);
    __syncthreads();
    int i = blockIdx.x * blockDim.x + t;
    if (i >= NNODES) return;
    float4 xv = ((const float4*)x)[i];
    float pr[20];
#pragma unroll
    for (int h = 0; h < 4; h++) {
#pragma unroll
        for (int a = 0; a < 4; a++) {
            float g = Cl[80 + h * 4 + a]
                    + Cl[h * 16 + a * 4 + 0] * xv.x + Cl[h * 16 + a * 4 + 1] * xv.y
                    + Cl[h * 16 + a * 4 + 2] * xv.z + Cl[h * 16 + a * 4 + 3] * xv.w;
            pr[h * 4 + a] = g * SCALE;
        }
        float e = Cl[96 + h]
                + Cl[64 + h * 4 + 0] * xv.x + Cl[64 + h * 4 + 1] * xv.y
                + Cl[64 + h * 4 + 2] * xv.z + Cl[64 + h * 4 + 3] * xv.w;
        pr[16 + h] = e * SCALE;
    }
    float4* pp = (float4*)(proj + (size_t)i * 20);
#pragma unroll
    for (int q = 0; q < 5; q++) pp[q] = ((const float4*)pr)[q];
}

// LDS counting-sort per 1600-edge chunk -> contiguous chunk write + one
// contiguous directory row. Single-wave shfl scan, 2 barriers.
__global__ __launch_bounds__(256) void k_binA(const int* __restrict__ ei,
                                              unsigned* __restrict__ chunks,
                                              unsigned* __restrict__ dir) {
    __shared__ unsigned raw[EPB];
    __shared__ unsigned srt[EPB];
    __shared__ int hist[512];
    __shared__ int ofs[512];
    int t = threadIdx.x, blk = blockIdx.x;
    hist[t] = 0; hist[t + 256] = 0;
    __syncthreads();
    int e0 = blk * EPB;
    for (int i = t; i < EPB; i += 256) {
        int r = ei[e0 + i];
        int c = ei[NEDGES + e0 + i];
        raw[i] = ((unsigned)c << 16) | (unsigned)r;
        atomicAdd(&hist[c >> 7], 1);
    }
    __syncthreads();
    if (t < 64) {
        int v[8], run = 0;
#pragma unroll
        for (int j = 0; j < 8; j++) { v[j] = hist[8 * t + j]; run += v[j]; }
        int p = run;
#pragma unroll
        for (int off = 1; off < 64; off <<= 1) {
            int u = __shfl_up(p, off, 64);
            if (t >= off) p += u;
        }
        int base = p - run;
#pragma unroll
        for (int j = 0; j < 8; j++) {
            hist[8 * t + j] = base;
            ofs[8 * t + j] = base;
            base += v[j];
        }
    }
    __syncthreads();
    for (int i = t; i < EPB; i += 256) {
        unsigned v = raw[i];
        int pos = atomicAdd(&ofs[v >> 23], 1);
        srt[pos] = v;
    }
    __syncthreads();
    uint4* co = (uint4*)(chunks + (size_t)blk * EPB);
    const uint4* si = (const uint4*)srt;
    for (int i = t; i < EPB / 4; i += 256) co[i] = si[i];
    for (int b = t; b < NBINS; b += 256) {
        int start = hist[b];
        int len = ofs[b] - start;
        dir[(size_t)blk * NBINS + b] = ((unsigned)start << 16) | (unsigned)len;
    }
}

// 782 blocks: bin = bid>>1, part = bid&1 owns chunks [part*500, +500).
// pe loaded COALESCED from proj (no weight processing here). Then R12's
// proven copy/sort/accumulate machinery.
__global__ __launch_bounds__(256) void k_accum(
        const unsigned* __restrict__ chunks, const unsigned* __restrict__ dir,
        const float* __restrict__ x, const float* __restrict__ proj,
        float* __restrict__ acc, float* __restrict__ pS) {
    __shared__ float pe[BINSZ][20];
    __shared__ unsigned raw[PCAP];
    __shared__ unsigned short srt[PCAP];
    __shared__ int hist[BINSZ];
    __shared__ int ofs[BINSZ];
    __shared__ int wsum[4];
    __shared__ float sw[4][4];
    int bid = blockIdx.x;
    int bin = bid >> 1;
    int part = bid & 1;
    int t = threadIdx.x;
    int base = bin << 7;
    if (t < BINSZ) hist[t] = 0;
    // coalesced pe load: 128 rows x 20 floats = 2560 floats = 640 float4
    {
        const float4* ps = (const float4*)(proj + (size_t)base * 20);
        int lim = (NNODES - base) * 5;       // float4s available (>=640 except last bin)
        if (lim > 640) lim = 640;
        float4* pd = (float4*)pe;
        for (int i = t; i < lim; i += 256) pd[i] = ps[i];
    }
    __syncthreads();
    // directory entries for this thread (chunks part*500 + {t, t+256})
    int blk0 = part * HALF + t;
    int blk1 = part * HALF + t + 256;
    unsigned d0 = 0, d1 = 0;
    int cnt = 0;
    if (t < HALF) { d0 = dir[(size_t)blk0 * NBINS + bin]; cnt += d0 & 0xFFFFu; }
    if (t + 256 < HALF) { d1 = dir[(size_t)blk1 * NBINS + bin]; cnt += d1 & 0xFFFFu; }
    int lane = t & 63, w = t >> 6;
    int p = cnt;
#pragma unroll
    for (int off = 1; off < 64; off <<= 1) {
        int u = __shfl_up(p, off, 64);
        if (lane >= off) p += u;
    }
    if (lane == 63) wsum[w] = p;
    __syncthreads();
    int wbase = 0;
#pragma unroll
    for (int ww = 0; ww < 4; ww++) wbase += (ww < w) ? wsum[ww] : 0;
    int off0 = wbase + p - cnt;
    int nval = wsum[0] + wsum[1] + wsum[2] + wsum[3];
    if (nval > PCAP) nval = PCAP;
    if (t < HALF) {
        int len = d0 & 0xFFFFu;
        const unsigned* cp = chunks + (size_t)blk0 * EPB + (d0 >> 16);
        for (int j = 0; j < len; j++) {
            unsigned v = cp[j];
            if (off0 < PCAP) raw[off0] = v;
            atomicAdd(&hist[(int)(v >> 16) - base], 1);
            off0++;
        }
    }
    if (t + 256 < HALF) {
        int len = d1 & 0xFFFFu;
        const unsigned* cp = chunks + (size_t)blk1 * EPB + (d1 >> 16);
        for (int j = 0; j < len; j++) {
            unsigned v = cp[j];
            if (off0 < PCAP) raw[off0] = v;
            atomicAdd(&hist[(int)(v >> 16) - base], 1);
            off0++;
        }
    }
    __syncthreads();
    if (t < 64) {
        int a0 = hist[2 * t], a1 = hist[2 * t + 1];
        int pair = a0 + a1;
        int pp = pair;
#pragma unroll
        for (int off = 1; off < 64; off <<= 1) {
            int u = __shfl_up(pp, off, 64);
            if (t >= off) pp += u;
        }
        int excl = pp - pair;
        hist[2 * t] = excl; hist[2 * t + 1] = excl + a0;
        ofs[2 * t] = excl;  ofs[2 * t + 1] = excl + a0;
    }
    __syncthreads();
    for (int i = t; i < nval; i += 256) {
        unsigned v = raw[i];
        int lc = (int)(v >> 16) - base;
        int pos = atomicAdd(&ofs[lc], 1);
        srt[pos] = (unsigned short)(v & 0xFFFFu);
    }
    __syncthreads();
    int nl = t >> 1;
    int sub = t & 1;
    int node = base + nl;
    int sBeg = hist[nl], sEnd = ofs[nl];
    float4 g0 = ((const float4*)pe[nl])[0];
    float4 g1 = ((const float4*)pe[nl])[1];
    float4 g2 = ((const float4*)pe[nl])[2];
    float4 g3 = ((const float4*)pe[nl])[3];
    float4 eh = ((const float4*)pe[nl])[4];
    float S0 = 0.f, S1 = 0.f, S2 = 0.f, S3 = 0.f;
    float4 y0 = {0, 0, 0, 0}, y1 = y0, y2 = y0, y3 = y0;
    for (int i = sBeg + sub; i < sEnd; i += 2) {
        int r = (int)srt[i];
        float4 xv = ((const float4*)x)[r];
        float p0 = __expf(xv.x * g0.x + xv.y * g0.y + xv.z * g0.z + xv.w * g0.w + eh.x);
        float p1 = __expf(xv.x * g1.x + xv.y * g1.y + xv.z * g1.z + xv.w * g1.w + eh.y);
        float p2 = __expf(xv.x * g2.x + xv.y * g2.y + xv.z * g2.z + xv.w * g2.w + eh.z);
        float p3 = __expf(xv.x * g3.x + xv.y * g3.y + xv.z * g3.z + xv.w * g3.w + eh.w);
        y0.x += p0 * xv.x; y0.y += p0 * xv.y; y0.z += p0 * xv.z; y0.w += p0 * xv.w;
        y1.x += p1 * xv.x; y1.y += p1 * xv.y; y1.z += p1 * xv.z; y1.w += p1 * xv.w;
        y2.x += p2 * xv.x; y2.y += p2 * xv.y; y2.z += p2 * xv.z; y2.w += p2 * xv.w;
        y3.x += p3 * xv.x; y3.y += p3 * xv.y; y3.z += p3 * xv.z; y3.w += p3 * xv.w;
        S0 += p0; S1 += p1; S2 += p2; S3 += p3;
    }
    y0.x += __shfl_xor(y0.x, 1); y0.y += __shfl_xor(y0.y, 1);
    y0.z += __shfl_xor(y0.z, 1); y0.w += __shfl_xor(y0.w, 1);
    y1.x += __shfl_xor(y1.x, 1); y1.y += __shfl_xor(y1.y, 1);
    y1.z += __shfl_xor(y1.z, 1); y1.w += __shfl_xor(y1.w, 1);
    y2.x += __shfl_xor(y2.x, 1); y2.y += __shfl_xor(y2.y, 1);
    y2.z += __shfl_xor(y2.z, 1); y2.w += __shfl_xor(y2.w, 1);
    y3.x += __shfl_xor(y3.x, 1); y3.y += __shfl_xor(y3.y, 1);
    y3.z += __shfl_xor(y3.z, 1); y3.w += __shfl_xor(y3.w, 1);
    S0 += __shfl_xor(S0, 1); S1 += __shfl_xor(S1, 1);
    S2 += __shfl_xor(S2, 1); S3 += __shfl_xor(S3, 1);
    if (node < NNODES) {
        float4* ap = (float4*)(acc + ((size_t)part * NNODES + node) * 20);
        float4 sv = {S0, S1, S2, S3};
        if (sub == 0) { ap[0] = y0; ap[2] = y2; ap[4] = sv; }
        else { ap[1] = y1; ap[3] = y3; }
    }
    float z0 = (sub == 0 && node < NNODES) ? S0 : 0.f;
    float z1 = (sub == 0 && node < NNODES) ? S1 : 0.f;
    float z2 = (sub == 0 && node < NNODES) ? S2 : 0.f;
    float z3 = (sub == 0 && node < NNODES) ? S3 : 0.f;
#pragma unroll
    for (int off = 1; off < 64; off <<= 1) {
        z0 += __shfl_xor(z0, off); z1 += __shfl_xor(z1, off);
        z2 += __shfl_xor(z2, off); z3 += __shfl_xor(z3, off);
    }
    if (lane == 0) { sw[w][0] = z0; sw[w][1] = z1; sw[w][2] = z2; sw[w][3] = z3; }
    __syncthreads();
    if (t == 0) {
        float4 v;
        v.x = sw[0][0] + sw[1][0] + sw[2][0] + sw[3][0];
        v.y = sw[0][1] + sw[1][1] + sw[2][1] + sw[3][1];
        v.z = sw[0][2] + sw[1][2] + sw[2][2] + sw[3][2];
        v.w = sw[0][3] + sw[1][3] + sw[2][3] + sw[3][3];
        ((float4*)pS)[bid] = v;
    }
}

// reduce per-block S partials + sum part accumulators + normalize + collapsed
// output projection + residual
__global__ __launch_bounds__(256) void k_out(
        const float* __restrict__ acc, const float* __restrict__ pS,
        const float* __restrict__ Wq, const float* __restrict__ bq,
        const float* __restrict__ Wk, const float* __restrict__ bk,
        const float* __restrict__ Wv, const float* __restrict__ bv,
        const float* __restrict__ Wo, const float* __restrict__ bo,
        const float* __restrict__ x, float* __restrict__ out) {
    __shared__ float Cl[192];
    __shared__ float sd[4][4];
    __shared__ float dd[4];
    int t = threadIdx.x;
    compute_C_entry(t, Wq, bq, Wk, bk, Wv, bv, Wo, Cl);
    float s0 = 0.f, s1 = 0.f, s2 = 0.f, s3 = 0.f;
    for (int i = t; i < 2 * NBINS; i += 256) {
        float4 v = ((const float4*)pS)[i];
        s0 += v.x; s1 += v.y; s2 += v.z; s3 += v.w;
    }
#pragma unroll
    for (int off = 1; off < 64; off <<= 1) {
        s0 += __shfl_xor(s0, off); s1 += __shfl_xor(s1, off);
        s2 += __shfl_xor(s2, off); s3 += __shfl_xor(s3, off);
    }
    int w = t >> 6;
    if ((t & 63) == 0) { sd[w][0] = s0; sd[w][1] = s1; sd[w][2] = s2; sd[w][3] = s3; }
    __syncthreads();
    if (t < 4) dd[t] = 1.f / (sd[0][t] + sd[1][t] + sd[2][t] + sd[3][t]);
    __syncthreads();
    int i = blockIdx.x * blockDim.x + t;
    if (i >= NNODES) return;
    const float4* a0 = (const float4*)(acc + (size_t)i * 20);
    const float4* a1 = (const float4*)(acc + ((size_t)NNODES + i) * 20);
    float4 y[4], S;
#pragma unroll
    for (int q = 0; q < 4; q++) {
        float4 u = a0[q], v = a1[q];
        y[q].x = u.x + v.x; y[q].y = u.y + v.y; y[q].z = u.z + v.z; y[q].w = u.w + v.w;
    }
    {
        float4 u = a0[4], v = a1[4];
        S.x = u.x + v.x; S.y = u.y + v.y; S.z = u.z + v.z; S.w = u.w + v.w;
    }
    float Sv[4] = {S.x, S.y, S.z, S.w};
    float di[4] = {dd[0], dd[1], dd[2], dd[3]};
    float o[4];
#pragma unroll
    for (int oo = 0; oo < 4; oo++) {
        float a = bo[oo];
#pragma unroll
        for (int h = 0; h < 4; h++) {
            float m = Cl[100 + h * 16 + oo * 4 + 0] * y[h].x
                    + Cl[100 + h * 16 + oo * 4 + 1] * y[h].y
                    + Cl[100 + h * 16 + oo * 4 + 2] * y[h].z
                    + Cl[100 + h * 16 + oo * 4 + 3] * y[h].w
                    + Cl[164 + h * 4 + oo] * Sv[h];
            a += di[h] * m;
        }
        o[oo] = a;
    }
    float4 xv = ((const float4*)x)[i];
    float4 ov;
    ov.x = o[0] + xv.x; ov.y = o[1] + xv.y; ov.z = o[2] + xv.z; ov.w = o[3] + xv.w;
    ((float4*)out)[i] = ov;
}

extern "C" void kernel_launch(void* const* d_in, const int* in_sizes, int n_in,
                              void* d_out, int out_size, void* d_ws, size_t ws_size,
                              hipStream_t stream) {
    const float* x = (const float*)d_in[0];
    const int* ei = (const int*)d_in[1];
    const float* Wq = (const float*)d_in[2];
    const float* bq = (const float*)d_in[3];
    const float* Wk = (const float*)d_in[4];
    const float* bk = (const float*)d_in[5];
    const float* Wv = (const float*)d_in[6];
    const float* bv = (const float*)d_in[7];
    const float* Wo = (const float*)d_in[8];
    const float* bo = (const float*)d_in[9];
    float* out = (float*)d_out;

    float* fws = (float*)d_ws;
    float* acc = fws;                                   // 2*NNODES*20 f32, 8 MB
    float* pS = acc + (size_t)2 * NNODES * 20;          // 782 float4 (pad 3200)
    float* proj = pS + 3200;                            // NNODES*20 f32, 4 MB
    unsigned* chunks = (unsigned*)(proj + (size_t)NNODES * 20);  // NEDGES u32
    unsigned* dir = chunks + (size_t)NEDGES;            // NBLK*NBINS u32

    k_proj<<<(NNODES + 255) / 256, 256, 0, stream>>>(x, Wq, bq, Wk, bk, Wv, bv, Wo, proj);
    k_binA<<<NBLK, 256, 0, stream>>>(ei, chunks, dir);
    k_accum<<<2 * NBINS, 256, 0, stream>>>(chunks, dir, x, proj, acc, pS);
    k_out<<<(NNODES + 255) / 256, 256, 0, stream>>>(acc, pS,
                                                    Wq, bq, Wk, bk, Wv, bv, Wo, bo, x, out);
}